// Round 1
// 668.071 us; speedup vs baseline: 1.0233x; 1.0233x over previous
//
#include <hip/hip_runtime.h>

// B=8, N=256, H=256
// out[b,i,h] = Ux[b,i,h] + (sum_j eg[b,i,j,h]*Vx[b,j,h]) / (1e-20 + sum_j eg[b,i,j,h])
// Ux is written directly to d_out by the GEMM; Vx (2 MB) lives in d_ws.

typedef float f4 __attribute__((ext_vector_type(4)));
typedef float f2 __attribute__((ext_vector_type(2)));

#define S36 36  // 32 k-floats + 4 pad: keeps 16B alignment, <=4-way read conflicts

__global__ __launch_bounds__(256) void gemm_uv(
    const float* __restrict__ x, const float* __restrict__ U_w,
    const float* __restrict__ U_b, const float* __restrict__ V_w,
    const float* __restrict__ V_b, float* __restrict__ Ux,
    float* __restrict__ Vx) {
  __shared__ float Xs[64 * S36];   // [m][k] 64x32
  __shared__ float Ws[32 * S36];   // [n][k] 32x32
  const int t  = threadIdx.x;
  const int gx = blockIdx.x;   // 0..15: n-tile (32 wide); gx<8 -> U, else V
  const int gy = blockIdx.y;   // 0..31: m-tile (64)
  const int m0 = gy * 64;
  const bool isU = (gx < 8);
  const float* Wsrc = isU ? U_w : V_w;
  const float* bsrc = isU ? U_b : V_b;
  const int n0 = (gx & 7) * 32;
  float* dst = isU ? Ux : Vx;

  const int tn = t & 15;   // n = 2*tn .. +1
  const int tm = t >> 4;   // m = 4*tm .. +3
  float acc[4][2] = {};

  const int lm = t >> 3;   // 0..31
  const int lc = t & 7;    // f4 index along k

  for (int k0 = 0; k0 < 256; k0 += 32) {
    #pragma unroll
    for (int r = 0; r < 2; ++r) {
      const int m = r * 32 + lm;
      f4 v = *(const f4*)(x + (m0 + m) * 256 + k0 + lc * 4);
      *(f4*)(&Xs[m * S36 + lc * 4]) = v;
    }
    {
      f4 v = *(const f4*)(Wsrc + (n0 + lm) * 256 + k0 + lc * 4);
      *(f4*)(&Ws[lm * S36 + lc * 4]) = v;
    }
    __syncthreads();
    #pragma unroll
    for (int kq = 0; kq < 8; ++kq) {
      f4 a0 = *(const f4*)(&Xs[(tm * 4 + 0) * S36 + kq * 4]);
      f4 a1 = *(const f4*)(&Xs[(tm * 4 + 1) * S36 + kq * 4]);
      f4 a2 = *(const f4*)(&Xs[(tm * 4 + 2) * S36 + kq * 4]);
      f4 a3 = *(const f4*)(&Xs[(tm * 4 + 3) * S36 + kq * 4]);
      f4 b0 = *(const f4*)(&Ws[(tn * 2 + 0) * S36 + kq * 4]);
      f4 b1 = *(const f4*)(&Ws[(tn * 2 + 1) * S36 + kq * 4]);
      acc[0][0] += a0.x*b0.x + a0.y*b0.y + a0.z*b0.z + a0.w*b0.w;
      acc[0][1] += a0.x*b1.x + a0.y*b1.y + a0.z*b1.z + a0.w*b1.w;
      acc[1][0] += a1.x*b0.x + a1.y*b0.y + a1.z*b0.z + a1.w*b0.w;
      acc[1][1] += a1.x*b1.x + a1.y*b1.y + a1.z*b1.z + a1.w*b1.w;
      acc[2][0] += a2.x*b0.x + a2.y*b0.y + a2.z*b0.z + a2.w*b0.w;
      acc[2][1] += a2.x*b1.x + a2.y*b1.y + a2.z*b1.z + a2.w*b1.w;
      acc[3][0] += a3.x*b0.x + a3.y*b0.y + a3.z*b0.z + a3.w*b0.w;
      acc[3][1] += a3.x*b1.x + a3.y*b1.y + a3.z*b1.z + a3.w*b1.w;
    }
    __syncthreads();
  }

  const float bb0 = bsrc[n0 + 2 * tn + 0];
  const float bb1 = bsrc[n0 + 2 * tn + 1];
  #pragma unroll
  for (int i = 0; i < 4; ++i) {
    f2 o;
    o.x = acc[i][0] + bb0;
    o.y = acc[i][1] + bb1;
    *(f2*)(dst + (m0 + 4 * tm + i) * 256 + n0 + 2 * tn) = o;
  }
}

// fuse_gate v2: one WAVE owns one (b,i) row.
//  - 64 lanes = 64 f4 = all 256 h; wave iterates all 256 j itself.
//  - consecutive unrolled j are 1024 B apart -> global-load *immediate*
//    offsets fold (13-bit signed limit is 4095 B; the old j-stride of
//    4096 B missed it and forced per-load 64-bit address recomputes).
//  - no LDS, no __syncthreads, no cross-wave reduce, no divergent tail.
//  - 512 blocks x 4 waves = 2048 waves total = 8 waves/CU, all resident
//    in a single round (old version needed 8192 waves / 2 rounds).
//  - 16 loads in flight per wave (8 eg HBM-stream + 8 Vx L2-hit);
//    two accumulator pairs break the FMA dependency chains.
__global__ __launch_bounds__(256) void fuse_gate(
    const float* __restrict__ eg, const float* __restrict__ Vx,
    float* __restrict__ out) {
  const int t    = threadIdx.x;
  const int lane = t & 63;          // f4 index along h (64 * 4 = 256 floats)
  const int w    = t >> 6;          // wave id within block: 0..3
  const int row  = blockIdx.x * 4 + w;   // 0..2047  (= b*256 + i)
  const int b    = row >> 8;

  const f4* eg4 = (const f4*)eg + (size_t)row * (256 * 64) + lane;
  const f4* vx4 = (const f4*)Vx + (size_t)b   * (256 * 64) + lane;

  f4 n0 = {0.f, 0.f, 0.f, 0.f}, n1 = {0.f, 0.f, 0.f, 0.f};
  f4 d0 = {0.f, 0.f, 0.f, 0.f}, d1 = {0.f, 0.f, 0.f, 0.f};

  #pragma unroll 1
  for (int j = 0; j < 256; j += 8) {
    const f4* ep = eg4 + j * 64;    // per-j f4 stride 64 -> 1024 B
    const f4* vp = vx4 + j * 64;
    f4 e0 = __builtin_nontemporal_load(ep + 0 * 64);
    f4 e1 = __builtin_nontemporal_load(ep + 1 * 64);
    f4 e2 = __builtin_nontemporal_load(ep + 2 * 64);
    f4 e3 = __builtin_nontemporal_load(ep + 3 * 64);
    f4 e4 = __builtin_nontemporal_load(ep + 4 * 64);
    f4 e5 = __builtin_nontemporal_load(ep + 5 * 64);
    f4 e6 = __builtin_nontemporal_load(ep + 6 * 64);
    f4 e7 = __builtin_nontemporal_load(ep + 7 * 64);
    f4 v0 = vp[0 * 64];
    f4 v1 = vp[1 * 64];
    f4 v2 = vp[2 * 64];
    f4 v3 = vp[3 * 64];
    f4 v4 = vp[4 * 64];
    f4 v5 = vp[5 * 64];
    f4 v6 = vp[6 * 64];
    f4 v7 = vp[7 * 64];
    n0 += e0 * v0;  d0 += e0;
    n1 += e1 * v1;  d1 += e1;
    n0 += e2 * v2;  d0 += e2;
    n1 += e3 * v3;  d1 += e3;
    n0 += e4 * v4;  d0 += e4;
    n1 += e5 * v5;  d1 += e5;
    n0 += e6 * v6;  d0 += e6;
    n1 += e7 * v7;  d1 += e7;
  }

  const f4 num = n0 + n1;
  const f4 den = d0 + d1;
  const size_t o = (size_t)row * 64 + lane;
  f4 u = ((const f4*)out)[o];
  f4 eps = {1e-20f, 1e-20f, 1e-20f, 1e-20f};
  ((f4*)out)[o] = u + num / (eps + den);
}

extern "C" void kernel_launch(void* const* d_in, const int* in_sizes, int n_in,
                              void* d_out, int out_size, void* d_ws, size_t ws_size,
                              hipStream_t stream) {
  const float* x   = (const float*)d_in[0];
  const float* eg  = (const float*)d_in[1];
  const float* U_w = (const float*)d_in[2];
  const float* U_b = (const float*)d_in[3];
  const float* V_w = (const float*)d_in[4];
  const float* V_b = (const float*)d_in[5];
  float* out = (float*)d_out;
  float* Vx  = (float*)d_ws;  // 2048*256*4 = 2 MB

  gemm_uv<<<dim3(16, 32), 256, 0, stream>>>(x, U_w, U_b, V_w, V_b, out, Vx);
  fuse_gate<<<dim3(512), 256, 0, stream>>>(eg, Vx, out);
}